// Round 4
// baseline (250.840 us; speedup 1.0000x reference)
//
#include <hip/hip_runtime.h>
#include <hip/hip_bf16.h>

#define T_TOK 2048
#define HDIM  2048
#define FDIM  1024
#define NEXP  8
#define KSEL  2
#define NENT  (T_TOK*KSEL)   // 4096 routing entries
#define WMAX  40             // max row-block work items (<= 32+7)

typedef __attribute__((ext_vector_type(8))) short   short8v;
typedef __attribute__((ext_vector_type(4))) float   floatx4;
typedef __attribute__((ext_vector_type(4))) unsigned short ushort4v;

__device__ __forceinline__ unsigned short f2bf(float f) {
  unsigned int u = __builtin_bit_cast(unsigned int, f);
  u += 0x7FFFu + ((u >> 16) & 1u);
  return (unsigned short)(u >> 16);
}

// async global->LDS, 16B per lane; LDS dest = wave-uniform base + lane*16
__device__ __forceinline__ void gll16(const void* g, void* l) {
  __builtin_amdgcn_global_load_lds(
      (const __attribute__((address_space(1))) unsigned int*)g,
      (__attribute__((address_space(3))) unsigned int*)l, 16, 0, 0);
}

// ---- workspace layout ----
// wsI[0:8) cnt | wsI[8:16) cursor | wsI[16:24) offsets | wsI[24] nWork
// wsI[48:88) work list (e<<8 | rowblock)
// wsI[128:128+4096) entry token | (float*)[4096] entry weight | [4096] inverse map
// byte 65536: hidden_bf (8 MiB) | act (8 MiB) | out_e (32 MiB)
#define ETOK_OFF 128

__global__ void k_count(const int* __restrict__ ids, int* __restrict__ wsI) {
  int g = blockIdx.x * 256 + threadIdx.x;
  if (g < NENT) atomicAdd(&wsI[ids[g] & 7], 1);
}

__global__ void k_scan(int* __restrict__ wsI) {
  int s = 0, nW = 0;
  int* wl = wsI + 48;
  for (int e = 0; e < NEXP; e++) {
    wsI[16 + e] = s;
    int c = wsI[e];
    s += c;
    int nb = (c + 127) >> 7;
    for (int rb = 0; rb < nb; rb++) wl[nW++] = (e << 8) | rb;
  }
  wsI[24] = nW;
}

__global__ void k_scatter(const int* __restrict__ ids, const float* __restrict__ tw,
                          int* __restrict__ wsI) {
  int g = blockIdx.x * 256 + threadIdx.x;
  if (g >= NENT) return;
  int e = ids[g] & 7;
  int pos = atomicAdd(&wsI[8 + e], 1);
  int idx = wsI[16 + e] + pos;
  int*   etok = wsI + ETOK_OFF;
  float* ew   = (float*)(wsI + ETOK_OFF + NENT);
  int*   inv  = wsI + ETOK_OFF + 2 * NENT;
  etok[idx] = g >> 1;
  ew[idx]   = tw[g];
  inv[g]    = idx;
}

__global__ __launch_bounds__(256) void k_cast_h(const float* __restrict__ h,
                                                unsigned short* __restrict__ o) {
  const int N = T_TOK * HDIM / 8;
  for (int c = blockIdx.x * 256 + threadIdx.x; c < N; c += 2048 * 256) {
    const floatx4 v0 = *(const floatx4*)(h + (size_t)c * 8);
    const floatx4 v1 = *(const floatx4*)(h + (size_t)c * 8 + 4);
    short8v r = { (short)f2bf(v0.x), (short)f2bf(v0.y), (short)f2bf(v0.z), (short)f2bf(v0.w),
                  (short)f2bf(v1.x), (short)f2bf(v1.y), (short)f2bf(v1.z), (short)f2bf(v1.w) };
    *(short8v*)(o + (size_t)c * 8) = r;
  }
}

// ---- GEMM1: act = silu(h@Wg^T)*(h@Wu^T); fused dequant; grid (WMAX, 32) ----
// Tile: 128 entries x 32 act-cols (B-tile = 32 gate rows + 32 up rows), BK=64.
__global__ __launch_bounds__(256, 4) void k_gemm1n(
    const unsigned short* __restrict__ hb,
    const float* __restrict__ wgu,
    const float* __restrict__ sgu,
    const int* __restrict__ wsI,
    unsigned short* __restrict__ act)
{
  if ((int)blockIdx.x >= wsI[24]) return;
  const int item = wsI[48 + blockIdx.x];
  const int e    = item >> 8;
  const int r0   = (item & 255) << 7;
  const int cnt  = wsI[e];
  const int off  = wsI[16 + e];
  const int c0   = blockIdx.y * 32;          // act col base
  const int* etok = wsI + ETOK_OFF;

  __shared__ unsigned short As[128][64];     // 16 KB
  __shared__ unsigned short Bs[64][64];      // 8 KB

  const int tid  = threadIdx.x;
  const int lane = tid & 63;
  const int w    = tid >> 6;
  const int wr   = (w >> 1) * 64;
  const int wc   = w & 1;
  const int kg   = lane >> 4;
  const int l15  = lane & 15;
  const int lr   = lane >> 3;
  const int lc   = lane & 7;

  // A: async global->LDS, pre-swizzled source
  unsigned int aoff[4];
#pragma unroll
  for (int i = 0; i < 4; i++) {
    int ra  = (w * 4 + i) * 8 + lr;
    int swz = (lc ^ (ra & 7)) * 8;
    int ent = r0 + ra; if (ent >= cnt) ent = cnt - 1;
    int tok = etok[off + ent];
    aoff[i] = (unsigned)tok * 2048u + (unsigned)swz;
  }

  // B: reg-staged fp32 with fused dequant; 2 16B-chunks per thread
  const float* bsrc[2];
  const float* bsrow[2];
  int bdst[2];
#pragma unroll
  for (int cc = 0; cc < 2; cc++) {
    int c   = tid + cc * 256;
    int row = c >> 3, ch = c & 7;
    int gr  = (row < 32) ? (c0 + row) : (1024 + c0 + row - 32);
    bsrc[cc]  = &wgu[((size_t)e * 2048 + gr) * 2048 + ch * 8];
    bsrow[cc] = &sgu[e * 256 + (gr >> 7) * 16];
    bdst[cc]  = row * 128 + ((ch ^ (row & 7)) << 4);
  }

  floatx4 acc[4][2] = {};

  for (int k0 = 0; k0 < HDIM; k0 += 64) {
#pragma unroll
    for (int i = 0; i < 4; i++)
      gll16(hb + aoff[i] + k0, (char*)As + (w * 4 + i) * 1024);
#pragma unroll
    for (int cc = 0; cc < 2; cc++) {
      const floatx4 v0 = *(const floatx4*)(bsrc[cc] + k0);
      const floatx4 v1 = *(const floatx4*)(bsrc[cc] + k0 + 4);
      float sc = bsrow[cc][k0 >> 7];
      short8v r = { (short)f2bf(v0.x*sc), (short)f2bf(v0.y*sc), (short)f2bf(v0.z*sc), (short)f2bf(v0.w*sc),
                    (short)f2bf(v1.x*sc), (short)f2bf(v1.y*sc), (short)f2bf(v1.z*sc), (short)f2bf(v1.w*sc) };
      *(short8v*)((char*)Bs + bdst[cc]) = r;
    }
    __syncthreads();

    const char* Ab = (const char*)As;
    const char* Bb = (const char*)Bs;
#pragma unroll
    for (int ks = 0; ks < 2; ks++) {
      short8v a[4], b[2];
#pragma unroll
      for (int m = 0; m < 4; m++) {
        int r = wr + m * 16 + l15;
        a[m] = *(const short8v*)(Ab + r * 128 + (((ks * 4 + kg) ^ (r & 7)) << 4));
      }
#pragma unroll
      for (int n = 0; n < 2; n++) {
        int rb = n * 32 + wc * 16 + l15;
        b[n] = *(const short8v*)(Bb + rb * 128 + (((ks * 4 + kg) ^ (rb & 7)) << 4));
      }
#pragma unroll
      for (int m = 0; m < 4; m++)
#pragma unroll
        for (int n = 0; n < 2; n++)
          acc[m][n] = __builtin_amdgcn_mfma_f32_16x16x32_bf16(a[m], b[n], acc[m][n], 0, 0, 0);
    }
    __syncthreads();
  }

#pragma unroll
  for (int m = 0; m < 4; m++) {
    int rbase = r0 + wr + m * 16 + kg * 4;
#pragma unroll
    for (int reg = 0; reg < 4; reg++) {
      int rr = rbase + reg;
      if (rr < cnt) {
        float g = acc[m][0][reg];
        float u = acc[m][1][reg];
        float a = g / (1.f + __expf(-g)) * u;
        act[(size_t)(off + rr) * FDIM + c0 + wc * 16 + l15] = f2bf(a);
      }
    }
  }
}

// ---- GEMM2: out_e = w_entry * (act @ Wdn^T); fused dequant; grid (WMAX, 32) ----
// Tile: 128 entries x 64 h-cols, BK=64.
__global__ __launch_bounds__(256, 4) void k_gemm2n(
    const float* __restrict__ wdn,
    const float* __restrict__ sdn,
    const int* __restrict__ wsI,
    const unsigned short* __restrict__ act,
    float* __restrict__ oe)
{
  if ((int)blockIdx.x >= wsI[24]) return;
  const int item = wsI[48 + blockIdx.x];
  const int e    = item >> 8;
  const int r0   = (item & 255) << 7;
  const int cnt  = wsI[e];
  const int off  = wsI[16 + e];
  const int c0   = blockIdx.y * 64;          // h col base
  const float* ew = (const float*)(wsI + ETOK_OFF + NENT);

  __shared__ unsigned short As[128][64];     // 16 KB
  __shared__ unsigned short Bs[64][64];      // 8 KB

  const int tid  = threadIdx.x;
  const int lane = tid & 63;
  const int w    = tid >> 6;
  const int wr   = (w >> 1) * 64;
  const int wc   = w & 1;
  const int kg   = lane >> 4;
  const int l15  = lane & 15;
  const int lr   = lane >> 3;
  const int lc   = lane & 7;

  unsigned int aoff[4];
#pragma unroll
  for (int i = 0; i < 4; i++) {
    int ra  = (w * 4 + i) * 8 + lr;
    int swz = (lc ^ (ra & 7)) * 8;
    int ent = r0 + ra; if (ent >= cnt) ent = cnt - 1;
    aoff[i] = (unsigned)(off + ent) * 1024u + (unsigned)swz;
  }

  const float* bsrc[2];
  const float* bsrow[2];
  int bdst[2];
#pragma unroll
  for (int cc = 0; cc < 2; cc++) {
    int c   = tid + cc * 256;
    int row = c >> 3, ch = c & 7;
    int gr  = c0 + row;
    bsrc[cc]  = &wdn[((size_t)e * 2048 + gr) * 1024 + ch * 8];
    bsrow[cc] = &sdn[e * 128 + (gr >> 7) * 8];
    bdst[cc]  = row * 128 + ((ch ^ (row & 7)) << 4);
  }

  floatx4 acc[4][2] = {};

  for (int k0 = 0; k0 < FDIM; k0 += 64) {
#pragma unroll
    for (int i = 0; i < 4; i++)
      gll16(act + aoff[i] + k0, (char*)As + (w * 4 + i) * 1024);
#pragma unroll
    for (int cc = 0; cc < 2; cc++) {
      const floatx4 v0 = *(const floatx4*)(bsrc[cc] + k0);
      const floatx4 v1 = *(const floatx4*)(bsrc[cc] + k0 + 4);
      float sc = bsrow[cc][k0 >> 7];
      short8v r = { (short)f2bf(v0.x*sc), (short)f2bf(v0.y*sc), (short)f2bf(v0.z*sc), (short)f2bf(v0.w*sc),
                    (short)f2bf(v1.x*sc), (short)f2bf(v1.y*sc), (short)f2bf(v1.z*sc), (short)f2bf(v1.w*sc) };
      *(short8v*)((char*)Bs + bdst[cc]) = r;
    }
    __syncthreads();

    const char* Ab = (const char*)As;
    const char* Bb = (const char*)Bs;
#pragma unroll
    for (int ks = 0; ks < 2; ks++) {
      short8v a[4], b[2];
#pragma unroll
      for (int m = 0; m < 4; m++) {
        int r = wr + m * 16 + l15;
        a[m] = *(const short8v*)(Ab + r * 128 + (((ks * 4 + kg) ^ (r & 7)) << 4));
      }
#pragma unroll
      for (int n = 0; n < 2; n++) {
        int rb = wc * 32 + n * 16 + l15;
        b[n] = *(const short8v*)(Bb + rb * 128 + (((ks * 4 + kg) ^ (rb & 7)) << 4));
      }
#pragma unroll
      for (int m = 0; m < 4; m++)
#pragma unroll
        for (int n = 0; n < 2; n++)
          acc[m][n] = __builtin_amdgcn_mfma_f32_16x16x32_bf16(a[m], b[n], acc[m][n], 0, 0, 0);
    }
    __syncthreads();
  }

#pragma unroll
  for (int m = 0; m < 4; m++) {
    int rbase = r0 + wr + m * 16 + kg * 4;
#pragma unroll
    for (int reg = 0; reg < 4; reg++) {
      int rr = rbase + reg;
      if (rr < cnt) {
        float wgt = ew[off + rr];
#pragma unroll
        for (int n = 0; n < 2; n++)
          oe[(size_t)(off + rr) * HDIM + c0 + wc * 32 + n * 16 + l15] = wgt * acc[m][n][reg];
      }
    }
  }
}

__global__ __launch_bounds__(256) void k_reduce(const int* __restrict__ wsI,
                                                const float* __restrict__ oe,
                                                float* __restrict__ out) {
  int i4 = blockIdx.x * 256 + threadIdx.x;
  if (i4 >= T_TOK * HDIM / 4) return;
  int t  = i4 >> 9;
  int h4 = (i4 & 511) * 4;
  const int* inv = wsI + ETOK_OFF + 2 * NENT;
  int e0 = inv[2 * t], e1 = inv[2 * t + 1];
  floatx4 a = *(const floatx4*)&oe[(size_t)e0 * HDIM + h4];
  floatx4 b = *(const floatx4*)&oe[(size_t)e1 * HDIM + h4];
  floatx4 r = a + b;
  *(floatx4*)&out[(size_t)t * HDIM + h4] = r;
}

// ================= fallback (round-1 passing kernels) =================
__global__ __launch_bounds__(256) void k_gemm1_fb(
    const float* __restrict__ hidden, const float* __restrict__ wgu,
    const float* __restrict__ sgu, const int* __restrict__ wsI,
    unsigned short* __restrict__ act)
{
  const int e = blockIdx.y; const int cnt = wsI[e];
  const int r0 = blockIdx.x * 128; if (r0 >= cnt) return;
  const int off = wsI[16 + e]; const int c0 = blockIdx.z * 64;
  const int* etok = wsI + ETOK_OFF;
  __shared__ unsigned short As[128][40]; __shared__ unsigned short Bs[128][40];
  const int tid = threadIdx.x, lane = tid & 63, wv = tid >> 6;
  const int wr = (wv >> 1) * 64, wc = wv & 1, kg = lane >> 4, l15 = lane & 15;
  floatx4 acc[4][4] = {};
  for (int k0 = 0; k0 < HDIM; k0 += 32) {
#pragma unroll
    for (int c = tid; c < 1024; c += 256) {
      int row = c >> 3, k4 = c & 7;
      int rg = r0 + row; if (rg >= cnt) rg = cnt - 1;
      int tok = etok[off + rg];
      const floatx4 v = *(const floatx4*)&hidden[(size_t)tok * HDIM + k0 + k4 * 4];
      ushort4v o = { f2bf(v.x), f2bf(v.y), f2bf(v.z), f2bf(v.w) };
      *(ushort4v*)&As[row][k4 * 4] = o;
    }
#pragma unroll
    for (int c = tid; c < 1024; c += 256) {
      int row = c >> 3, k4 = c & 7;
      int gr = (row < 64) ? (c0 + row) : (FDIM + c0 + row - 64);
      float s = sgu[e * 256 + (gr >> 7) * 16 + (k0 >> 7)];
      const floatx4 v = *(const floatx4*)&wgu[((size_t)e * 2048 + gr) * HDIM + k0 + k4 * 4];
      ushort4v o = { f2bf(v.x * s), f2bf(v.y * s), f2bf(v.z * s), f2bf(v.w * s) };
      *(ushort4v*)&Bs[row][k4 * 4] = o;
    }
    __syncthreads();
    short8v a[4], b[4];
#pragma unroll
    for (int m = 0; m < 4; m++) a[m] = *(const short8v*)&As[wr + m * 16 + l15][kg * 8];
#pragma unroll
    for (int n = 0; n < 4; n++) {
      int br = (n < 2) ? (wc * 32 + n * 16) : (64 + wc * 32 + (n - 2) * 16);
      b[n] = *(const short8v*)&Bs[br + l15][kg * 8];
    }
#pragma unroll
    for (int m = 0; m < 4; m++)
#pragma unroll
      for (int n = 0; n < 4; n++)
        acc[m][n] = __builtin_amdgcn_mfma_f32_16x16x32_bf16(a[m], b[n], acc[m][n], 0, 0, 0);
    __syncthreads();
  }
#pragma unroll
  for (int m = 0; m < 4; m++) {
    int rbase = r0 + wr + m * 16 + kg * 4;
#pragma unroll
    for (int reg = 0; reg < 4; reg++) {
      int rr = rbase + reg;
      if (rr < cnt) {
#pragma unroll
        for (int n = 0; n < 2; n++) {
          float g = acc[m][n][reg], u = acc[m][n + 2][reg];
          float a = g / (1.f + expf(-g)) * u;
          act[(size_t)(off + rr) * FDIM + c0 + wc * 32 + n * 16 + l15] = f2bf(a);
        }
      }
    }
  }
}

__global__ __launch_bounds__(256) void k_gemm2_fb(
    const float* __restrict__ wdn, const float* __restrict__ sdn,
    const int* __restrict__ wsI, const unsigned short* __restrict__ act,
    float* __restrict__ out)
{
  const int e = blockIdx.y; const int cnt = wsI[e];
  const int r0 = blockIdx.x * 128; if (r0 >= cnt) return;
  const int off = wsI[16 + e]; const int c0 = blockIdx.z * 128;
  const int* etok = wsI + ETOK_OFF;
  const float* ew = (const float*)(wsI + ETOK_OFF + NENT);
  __shared__ unsigned short As[128][40]; __shared__ unsigned short Bs[128][40];
  const int tid = threadIdx.x, lane = tid & 63, wv = tid >> 6;
  const int wr = (wv >> 1) * 64, wc = wv & 1, kg = lane >> 4, l15 = lane & 15;
  floatx4 acc[4][4] = {};
  for (int k0 = 0; k0 < FDIM; k0 += 32) {
#pragma unroll
    for (int c = tid; c < 512; c += 256) {
      int row = c >> 2, k8 = c & 3;
      int rg = r0 + row; if (rg >= cnt) rg = cnt - 1;
      short8v v = *(const short8v*)&act[(size_t)(off + rg) * FDIM + k0 + k8 * 8];
      *(short8v*)&As[row][k8 * 8] = v;
    }
#pragma unroll
    for (int c = tid; c < 1024; c += 256) {
      int row = c >> 3, k4 = c & 7;
      int gr = c0 + row;
      float s = sdn[e * 128 + (gr >> 7) * 8 + (k0 >> 7)];
      const floatx4 v = *(const floatx4*)&wdn[((size_t)e * HDIM + gr) * FDIM + k0 + k4 * 4];
      ushort4v o = { f2bf(v.x * s), f2bf(v.y * s), f2bf(v.z * s), f2bf(v.w * s) };
      *(ushort4v*)&Bs[row][k4 * 4] = o;
    }
    __syncthreads();
    short8v a[4], b[4];
#pragma unroll
    for (int m = 0; m < 4; m++) a[m] = *(const short8v*)&As[wr + m * 16 + l15][kg * 8];
#pragma unroll
    for (int n = 0; n < 4; n++) b[n] = *(const short8v*)&Bs[wc * 64 + n * 16 + l15][kg * 8];
#pragma unroll
    for (int m = 0; m < 4; m++)
#pragma unroll
      for (int n = 0; n < 4; n++)
        acc[m][n] = __builtin_amdgcn_mfma_f32_16x16x32_bf16(a[m], b[n], acc[m][n], 0, 0, 0);
    __syncthreads();
  }
#pragma unroll
  for (int m = 0; m < 4; m++) {
    int rbase = r0 + wr + m * 16 + kg * 4;
#pragma unroll
    for (int reg = 0; reg < 4; reg++) {
      int rr = rbase + reg;
      if (rr < cnt) {
        int tok = etok[off + rr];
        float ww = ew[off + rr];
#pragma unroll
        for (int n = 0; n < 4; n++)
          atomicAdd(&out[(size_t)tok * HDIM + c0 + wc * 64 + n * 16 + l15], ww * acc[m][n][reg]);
      }
    }
  }
}

extern "C" void kernel_launch(void* const* d_in, const int* in_sizes, int n_in,
                              void* d_out, int out_size, void* d_ws, size_t ws_size,
                              hipStream_t stream) {
  const float* hidden = (const float*)d_in[0];
  const float* tw     = (const float*)d_in[1];
  const int*   ids    = (const int*)d_in[2];
  const float* wgu    = (const float*)d_in[3];
  const float* sgu    = (const float*)d_in[4];
  const float* wdn    = (const float*)d_in[5];
  const float* sdn    = (const float*)d_in[6];
  float* out = (float*)d_out;
  int* wsI = (int*)d_ws;

  hipMemsetAsync(d_ws, 0, 512, stream);
  k_count  <<<16, 256, 0, stream>>>(ids, wsI);
  k_scan   <<<1, 1, 0, stream>>>(wsI);
  k_scatter<<<16, 256, 0, stream>>>(ids, tw, wsI);

  const size_t NEED = 65536ull + (52ull << 20);
  if (ws_size >= NEED) {
    unsigned short* hb  = (unsigned short*)((char*)d_ws + 65536);
    unsigned short* act = hb + (size_t)T_TOK * HDIM;
    float*          oe  = (float*)(act + (size_t)NENT * FDIM);

    k_cast_h<<<2048, 256, 0, stream>>>(hidden, hb);

    dim3 g1(WMAX, 32);
    k_gemm1n<<<g1, 256, 0, stream>>>(hb, wgu, sgu, wsI, act);
    dim3 g2(WMAX, 32);
    k_gemm2n<<<g2, 256, 0, stream>>>(wdn, sdn, wsI, act, oe);
    k_reduce<<<T_TOK * HDIM / 4 / 256, 256, 0, stream>>>(wsI, oe, out);
  } else {
    unsigned short* act = (unsigned short*)((char*)d_ws + 65536);
    hipMemsetAsync(d_out, 0, (size_t)T_TOK * HDIM * sizeof(float), stream);
    dim3 g1(NENT / 128, NEXP, FDIM / 64);
    k_gemm1_fb<<<g1, 256, 0, stream>>>(hidden, wgu, sgu, wsI, act);
    dim3 g2(NENT / 128, NEXP, HDIM / 128);
    k_gemm2_fb<<<g2, 256, 0, stream>>>(wdn, sdn, wsI, act, out);
  }
}

// Round 5
// 222.126 us; speedup vs baseline: 1.1293x; 1.1293x over previous
//
#include <hip/hip_runtime.h>
#include <hip/hip_bf16.h>

#define T_TOK 2048
#define HDIM  2048
#define FDIM  1024
#define NEXP  8
#define KSEL  2
#define NENT  (T_TOK*KSEL)   // 4096 routing entries
#define WMAX  16             // max 512-row work items: sum ceil(cnt/512) <= 8+8

typedef __attribute__((ext_vector_type(8))) short   short8v;
typedef __attribute__((ext_vector_type(4))) float   floatx4;
typedef __attribute__((ext_vector_type(4))) unsigned short ushort4v;

__device__ __forceinline__ unsigned short f2bf(float f) {
  unsigned int u = __builtin_bit_cast(unsigned int, f);
  u += 0x7FFFu + ((u >> 16) & 1u);
  return (unsigned short)(u >> 16);
}

__device__ __forceinline__ void gll16(const void* g, void* l) {
  __builtin_amdgcn_global_load_lds(
      (const __attribute__((address_space(1))) unsigned int*)g,
      (__attribute__((address_space(3))) unsigned int*)l, 16, 0, 0);
}

// ---- workspace layout ----
// wsI[0:8) cnt | wsI[8:16) cursor | wsI[16:24) offsets | wsI[24] nWork(512-row items)
// wsI[48:64) work list (e<<8 | superblock)
// wsI[128:128+4096) entry token | (float*)[4096] entry weight | [4096] inverse map
// byte 65536: hidden_bf (8 MiB) | act (8 MiB) | out_e (32 MiB)
#define ETOK_OFF 128

__global__ void k_count(const int* __restrict__ ids, int* __restrict__ wsI) {
  int g = blockIdx.x * 256 + threadIdx.x;
  if (g < NENT) atomicAdd(&wsI[ids[g] & 7], 1);
}

__global__ void k_scan(int* __restrict__ wsI) {
  int s = 0, nW = 0;
  int* wl = wsI + 48;
  for (int e = 0; e < NEXP; e++) {
    wsI[16 + e] = s;
    int c = wsI[e];
    s += c;
    int nb = (c + 511) >> 9;
    for (int sb = 0; sb < nb; sb++) wl[nW++] = (e << 8) | sb;
  }
  wsI[24] = nW;
}

__global__ void k_scatter(const int* __restrict__ ids, const float* __restrict__ tw,
                          int* __restrict__ wsI) {
  int g = blockIdx.x * 256 + threadIdx.x;
  if (g >= NENT) return;
  int e = ids[g] & 7;
  int pos = atomicAdd(&wsI[8 + e], 1);
  int idx = wsI[16 + e] + pos;
  int*   etok = wsI + ETOK_OFF;
  float* ew   = (float*)(wsI + ETOK_OFF + NENT);
  int*   inv  = wsI + ETOK_OFF + 2 * NENT;
  etok[idx] = g >> 1;
  ew[idx]   = tw[g];
  inv[g]    = idx;
}

__global__ __launch_bounds__(256) void k_cast_h(const float* __restrict__ h,
                                                unsigned short* __restrict__ o) {
  const int N = T_TOK * HDIM / 8;
  for (int c = blockIdx.x * 256 + threadIdx.x; c < N; c += 2048 * 256) {
    const floatx4 v0 = *(const floatx4*)(h + (size_t)c * 8);
    const floatx4 v1 = *(const floatx4*)(h + (size_t)c * 8 + 4);
    short8v r = { (short)f2bf(v0.x), (short)f2bf(v0.y), (short)f2bf(v0.z), (short)f2bf(v0.w),
                  (short)f2bf(v1.x), (short)f2bf(v1.y), (short)f2bf(v1.z), (short)f2bf(v1.w) };
    *(short8v*)(o + (size_t)c * 8) = r;
  }
}

// ---- GEMM1: act = silu(h@Wg^T)*(h@Wu^T); M=512 superblock; fused dequant ----
// grid (WMAX, 32): y = 32-col act tile (B = 32 gate rows + 32 up rows), BK=64.
__global__ __launch_bounds__(256, 2) void k_gemm1n(
    const unsigned short* __restrict__ hb,
    const float* __restrict__ wgu,
    const float* __restrict__ sgu,
    const int* __restrict__ wsI,
    unsigned short* __restrict__ act)
{
  if ((int)blockIdx.x >= wsI[24]) return;
  const int item = wsI[48 + blockIdx.x];
  const int e    = item >> 8;
  const int r0   = (item & 255) << 9;        // superblock base (512 rows)
  const int cnt  = wsI[e];
  const int off  = wsI[16 + e];
  const int c0   = blockIdx.y * 32;          // act col base
  const int* etok = wsI + ETOK_OFF;
  const int nsub = min(4, (cnt - r0 + 127) >> 7);

  __shared__ unsigned short As[512][64];     // 64 KB
  __shared__ unsigned short Bs[64][64];      // 8 KB

  const int tid  = threadIdx.x;
  const int lane = tid & 63;
  const int w    = tid >> 6;
  const int wr   = (w >> 1) * 64;
  const int wc   = w & 1;
  const int kg   = lane >> 4;
  const int l15  = lane & 15;
  const int lr   = lane >> 3;
  const int lc   = lane & 7;

  // A offsets: wave w stages sub-block w (rows w*128 .. w*128+127)
  unsigned int aoff[16];
#pragma unroll
  for (int i = 0; i < 16; i++) {
    int ra  = w * 128 + i * 8 + lr;
    int swz = (lc ^ (ra & 7)) * 8;
    int ent = r0 + ra; if (ent >= cnt) ent = cnt - 1;
    int tok = etok[off + ent];
    aoff[i] = (unsigned)tok * 2048u + (unsigned)swz;
  }

  // B: reg-staged fp32 with fused dequant
  const float* bsrc[2];
  const float* bsrow[2];
  int bdst[2];
#pragma unroll
  for (int cc = 0; cc < 2; cc++) {
    int c   = tid + cc * 256;
    int row = c >> 3, ch = c & 7;
    int gr  = (row < 32) ? (c0 + row) : (1024 + c0 + row - 32);
    bsrc[cc]  = &wgu[((size_t)e * 2048 + gr) * 2048 + ch * 8];
    bsrow[cc] = &sgu[e * 256 + (gr >> 7) * 16];
    bdst[cc]  = row * 128 + ((ch ^ (row & 7)) << 4);
  }

  floatx4 acc[4][4][2] = {};

  for (int k0 = 0; k0 < HDIM; k0 += 64) {
    if (w < nsub) {
#pragma unroll
      for (int i = 0; i < 16; i++)
        gll16(hb + aoff[i] + k0, (char*)As + (w * 16 + i) * 1024);
    }
#pragma unroll
    for (int cc = 0; cc < 2; cc++) {
      const floatx4 v0 = *(const floatx4*)(bsrc[cc] + k0);
      const floatx4 v1 = *(const floatx4*)(bsrc[cc] + k0 + 4);
      float sc = bsrow[cc][k0 >> 7];
      short8v r = { (short)f2bf(v0.x*sc), (short)f2bf(v0.y*sc), (short)f2bf(v0.z*sc), (short)f2bf(v0.w*sc),
                    (short)f2bf(v1.x*sc), (short)f2bf(v1.y*sc), (short)f2bf(v1.z*sc), (short)f2bf(v1.w*sc) };
      *(short8v*)((char*)Bs + bdst[cc]) = r;
    }
    __syncthreads();

    const char* Ab = (const char*)As;
    const char* Bb = (const char*)Bs;
#pragma unroll
    for (int ks = 0; ks < 2; ks++) {
      short8v b[2];
#pragma unroll
      for (int n = 0; n < 2; n++) {
        int rb = n * 32 + wc * 16 + l15;
        b[n] = *(const short8v*)(Bb + rb * 128 + (((ks * 4 + kg) ^ (rb & 7)) << 4));
      }
#pragma unroll
      for (int sub = 0; sub < 4; sub++) {
        if (sub < nsub) {
          short8v a[4];
#pragma unroll
          for (int m = 0; m < 4; m++) {
            int r = sub * 128 + wr + m * 16 + l15;
            a[m] = *(const short8v*)(Ab + r * 128 + (((ks * 4 + kg) ^ (r & 7)) << 4));
          }
#pragma unroll
          for (int m = 0; m < 4; m++)
#pragma unroll
            for (int n = 0; n < 2; n++)
              acc[sub][m][n] = __builtin_amdgcn_mfma_f32_16x16x32_bf16(a[m], b[n], acc[sub][m][n], 0, 0, 0);
        }
      }
    }
    __syncthreads();
  }

#pragma unroll
  for (int sub = 0; sub < 4; sub++) {
    if (sub < nsub) {
#pragma unroll
      for (int m = 0; m < 4; m++) {
        int rbase = r0 + sub * 128 + wr + m * 16 + kg * 4;
#pragma unroll
        for (int reg = 0; reg < 4; reg++) {
          int rr = rbase + reg;
          if (rr < cnt) {
            float g = acc[sub][m][0][reg];
            float u = acc[sub][m][1][reg];
            float a = g / (1.f + __expf(-g)) * u;
            act[(size_t)(off + rr) * FDIM + c0 + wc * 16 + l15] = f2bf(a);
          }
        }
      }
    }
  }
}

// ---- GEMM2: out_e = w_entry * (act @ Wdn^T); M=512; fused dequant ----
// grid (WMAX, 32): y = 64 h-cols, BK=64.
__global__ __launch_bounds__(256, 2) void k_gemm2n(
    const float* __restrict__ wdn,
    const float* __restrict__ sdn,
    const int* __restrict__ wsI,
    const unsigned short* __restrict__ act,
    float* __restrict__ oe)
{
  if ((int)blockIdx.x >= wsI[24]) return;
  const int item = wsI[48 + blockIdx.x];
  const int e    = item >> 8;
  const int r0   = (item & 255) << 9;
  const int cnt  = wsI[e];
  const int off  = wsI[16 + e];
  const int c0   = blockIdx.y * 64;
  const float* ew = (const float*)(wsI + ETOK_OFF + NENT);
  const int nsub = min(4, (cnt - r0 + 127) >> 7);

  __shared__ unsigned short As[512][64];     // 64 KB
  __shared__ unsigned short Bs[64][64];      // 8 KB

  const int tid  = threadIdx.x;
  const int lane = tid & 63;
  const int w    = tid >> 6;
  const int wr   = (w >> 1) * 64;
  const int wc   = w & 1;
  const int kg   = lane >> 4;
  const int l15  = lane & 15;
  const int lr   = lane >> 3;
  const int lc   = lane & 7;

  unsigned int aoff[16];
#pragma unroll
  for (int i = 0; i < 16; i++) {
    int ra  = w * 128 + i * 8 + lr;
    int swz = (lc ^ (ra & 7)) * 8;
    int ent = r0 + ra; if (ent >= cnt) ent = cnt - 1;
    aoff[i] = (unsigned)(off + ent) * 1024u + (unsigned)swz;
  }

  const float* bsrc[2];
  const float* bsrow[2];
  int bdst[2];
#pragma unroll
  for (int cc = 0; cc < 2; cc++) {
    int c   = tid + cc * 256;
    int row = c >> 3, ch = c & 7;
    int gr  = c0 + row;
    bsrc[cc]  = &wdn[((size_t)e * 2048 + gr) * 1024 + ch * 8];
    bsrow[cc] = &sdn[e * 128 + (gr >> 7) * 8];
    bdst[cc]  = row * 128 + ((ch ^ (row & 7)) << 4);
  }

  floatx4 acc[4][4][2] = {};

  for (int k0 = 0; k0 < FDIM; k0 += 64) {
    if (w < nsub) {
#pragma unroll
      for (int i = 0; i < 16; i++)
        gll16(act + aoff[i] + k0, (char*)As + (w * 16 + i) * 1024);
    }
#pragma unroll
    for (int cc = 0; cc < 2; cc++) {
      const floatx4 v0 = *(const floatx4*)(bsrc[cc] + k0);
      const floatx4 v1 = *(const floatx4*)(bsrc[cc] + k0 + 4);
      float sc = bsrow[cc][k0 >> 7];
      short8v r = { (short)f2bf(v0.x*sc), (short)f2bf(v0.y*sc), (short)f2bf(v0.z*sc), (short)f2bf(v0.w*sc),
                    (short)f2bf(v1.x*sc), (short)f2bf(v1.y*sc), (short)f2bf(v1.z*sc), (short)f2bf(v1.w*sc) };
      *(short8v*)((char*)Bs + bdst[cc]) = r;
    }
    __syncthreads();

    const char* Ab = (const char*)As;
    const char* Bb = (const char*)Bs;
#pragma unroll
    for (int ks = 0; ks < 2; ks++) {
      short8v b[2];
#pragma unroll
      for (int n = 0; n < 2; n++) {
        int rb = wc * 32 + n * 16 + l15;
        b[n] = *(const short8v*)(Bb + rb * 128 + (((ks * 4 + kg) ^ (rb & 7)) << 4));
      }
#pragma unroll
      for (int sub = 0; sub < 4; sub++) {
        if (sub < nsub) {
          short8v a[4];
#pragma unroll
          for (int m = 0; m < 4; m++) {
            int r = sub * 128 + wr + m * 16 + l15;
            a[m] = *(const short8v*)(Ab + r * 128 + (((ks * 4 + kg) ^ (r & 7)) << 4));
          }
#pragma unroll
          for (int m = 0; m < 4; m++)
#pragma unroll
            for (int n = 0; n < 2; n++)
              acc[sub][m][n] = __builtin_amdgcn_mfma_f32_16x16x32_bf16(a[m], b[n], acc[sub][m][n], 0, 0, 0);
        }
      }
    }
    __syncthreads();
  }

#pragma unroll
  for (int sub = 0; sub < 4; sub++) {
    if (sub < nsub) {
#pragma unroll
      for (int m = 0; m < 4; m++) {
        int rbase = r0 + sub * 128 + wr + m * 16 + kg * 4;
#pragma unroll
        for (int reg = 0; reg < 4; reg++) {
          int rr = rbase + reg;
          if (rr < cnt) {
            float wgt = ew[off + rr];
#pragma unroll
            for (int n = 0; n < 2; n++)
              oe[(size_t)(off + rr) * HDIM + c0 + wc * 32 + n * 16 + l15] = wgt * acc[sub][m][n][reg];
          }
        }
      }
    }
  }
}

__global__ __launch_bounds__(256) void k_reduce(const int* __restrict__ wsI,
                                                const float* __restrict__ oe,
                                                float* __restrict__ out) {
  int i4 = blockIdx.x * 256 + threadIdx.x;
  if (i4 >= T_TOK * HDIM / 4) return;
  int t  = i4 >> 9;
  int h4 = (i4 & 511) * 4;
  const int* inv = wsI + ETOK_OFF + 2 * NENT;
  int e0 = inv[2 * t], e1 = inv[2 * t + 1];
  floatx4 a = *(const floatx4*)&oe[(size_t)e0 * HDIM + h4];
  floatx4 b = *(const floatx4*)&oe[(size_t)e1 * HDIM + h4];
  floatx4 r = a + b;
  *(floatx4*)&out[(size_t)t * HDIM + h4] = r;
}

// ================= fallback (round-1 passing kernels) =================
__global__ __launch_bounds__(256) void k_gemm1_fb(
    const float* __restrict__ hidden, const float* __restrict__ wgu,
    const float* __restrict__ sgu, const int* __restrict__ wsI,
    unsigned short* __restrict__ act)
{
  const int e = blockIdx.y; const int cnt = wsI[e];
  const int r0 = blockIdx.x * 128; if (r0 >= cnt) return;
  const int off = wsI[16 + e]; const int c0 = blockIdx.z * 64;
  const int* etok = wsI + ETOK_OFF;
  __shared__ unsigned short As[128][40]; __shared__ unsigned short Bs[128][40];
  const int tid = threadIdx.x, lane = tid & 63, wv = tid >> 6;
  const int wr = (wv >> 1) * 64, wc = wv & 1, kg = lane >> 4, l15 = lane & 15;
  floatx4 acc[4][4] = {};
  for (int k0 = 0; k0 < HDIM; k0 += 32) {
#pragma unroll
    for (int c = tid; c < 1024; c += 256) {
      int row = c >> 3, k4 = c & 7;
      int rg = r0 + row; if (rg >= cnt) rg = cnt - 1;
      int tok = etok[off + rg];
      const floatx4 v = *(const floatx4*)&hidden[(size_t)tok * HDIM + k0 + k4 * 4];
      ushort4v o = { f2bf(v.x), f2bf(v.y), f2bf(v.z), f2bf(v.w) };
      *(ushort4v*)&As[row][k4 * 4] = o;
    }
#pragma unroll
    for (int c = tid; c < 1024; c += 256) {
      int row = c >> 3, k4 = c & 7;
      int gr = (row < 64) ? (c0 + row) : (FDIM + c0 + row - 64);
      float s = sgu[e * 256 + (gr >> 7) * 16 + (k0 >> 7)];
      const floatx4 v = *(const floatx4*)&wgu[((size_t)e * 2048 + gr) * HDIM + k0 + k4 * 4];
      ushort4v o = { f2bf(v.x * s), f2bf(v.y * s), f2bf(v.z * s), f2bf(v.w * s) };
      *(ushort4v*)&Bs[row][k4 * 4] = o;
    }
    __syncthreads();
    short8v a[4], b[4];
#pragma unroll
    for (int m = 0; m < 4; m++) a[m] = *(const short8v*)&As[wr + m * 16 + l15][kg * 8];
#pragma unroll
    for (int n = 0; n < 4; n++) {
      int br = (n < 2) ? (wc * 32 + n * 16) : (64 + wc * 32 + (n - 2) * 16);
      b[n] = *(const short8v*)&Bs[br + l15][kg * 8];
    }
#pragma unroll
    for (int m = 0; m < 4; m++)
#pragma unroll
      for (int n = 0; n < 4; n++)
        acc[m][n] = __builtin_amdgcn_mfma_f32_16x16x32_bf16(a[m], b[n], acc[m][n], 0, 0, 0);
    __syncthreads();
  }
#pragma unroll
  for (int m = 0; m < 4; m++) {
    int rbase = r0 + wr + m * 16 + kg * 4;
#pragma unroll
    for (int reg = 0; reg < 4; reg++) {
      int rr = rbase + reg;
      if (rr < cnt) {
#pragma unroll
        for (int n = 0; n < 2; n++) {
          float g = acc[m][n][reg], u = acc[m][n + 2][reg];
          float a = g / (1.f + expf(-g)) * u;
          act[(size_t)(off + rr) * FDIM + c0 + wc * 32 + n * 16 + l15] = f2bf(a);
        }
      }
    }
  }
}

__global__ __launch_bounds__(256) void k_gemm2_fb(
    const float* __restrict__ wdn, const float* __restrict__ sdn,
    const int* __restrict__ wsI, const unsigned short* __restrict__ act,
    float* __restrict__ out)
{
  const int e = blockIdx.y; const int cnt = wsI[e];
  const int r0 = blockIdx.x * 128; if (r0 >= cnt) return;
  const int off = wsI[16 + e]; const int c0 = blockIdx.z * 128;
  const int* etok = wsI + ETOK_OFF;
  const float* ew = (const float*)(wsI + ETOK_OFF + NENT);
  __shared__ unsigned short As[128][40]; __shared__ unsigned short Bs[128][40];
  const int tid = threadIdx.x, lane = tid & 63, wv = tid >> 6;
  const int wr = (wv >> 1) * 64, wc = wv & 1, kg = lane >> 4, l15 = lane & 15;
  floatx4 acc[4][4] = {};
  for (int k0 = 0; k0 < FDIM; k0 += 32) {
#pragma unroll
    for (int c = tid; c < 512; c += 256) {
      int row = c >> 2, k8 = c & 3;
      int rg = r0 + row; if (rg >= cnt) rg = cnt - 1;
      short8v v = *(const short8v*)&act[(size_t)(off + rg) * FDIM + k0 + k8 * 8];
      *(short8v*)&As[row][k8 * 8] = v;
    }
#pragma unroll
    for (int c = tid; c < 1024; c += 256) {
      int row = c >> 3, k4 = c & 7;
      int gr = c0 + row;
      float s = sdn[e * 128 + (gr >> 7) * 8 + (k0 >> 7)];
      const floatx4 v = *(const floatx4*)&wdn[((size_t)e * HDIM + gr) * FDIM + k0 + k4 * 4];
      ushort4v o = { f2bf(v.x * s), f2bf(v.y * s), f2bf(v.z * s), f2bf(v.w * s) };
      *(ushort4v*)&Bs[row][k4 * 4] = o;
    }
    __syncthreads();
    short8v a[4], b[4];
#pragma unroll
    for (int m = 0; m < 4; m++) a[m] = *(const short8v*)&As[wr + m * 16 + l15][kg * 8];
#pragma unroll
    for (int n = 0; n < 4; n++) b[n] = *(const short8v*)&Bs[wc * 64 + n * 16 + l15][kg * 8];
#pragma unroll
    for (int m = 0; m < 4; m++)
#pragma unroll
      for (int n = 0; n < 4; n++)
        acc[m][n] = __builtin_amdgcn_mfma_f32_16x16x32_bf16(a[m], b[n], acc[m][n], 0, 0, 0);
    __syncthreads();
  }
#pragma unroll
  for (int m = 0; m < 4; m++) {
    int rbase = r0 + wr + m * 16 + kg * 4;
#pragma unroll
    for (int reg = 0; reg < 4; reg++) {
      int rr = rbase + reg;
      if (rr < cnt) {
        int tok = etok[off + rr];
        float ww = ew[off + rr];
#pragma unroll
        for (int n = 0; n < 4; n++)
          atomicAdd(&out[(size_t)tok * HDIM + c0 + wc * 64 + n * 16 + l15], ww * acc[m][n][reg]);
      }
    }
  }
}

extern "C" void kernel_launch(void* const* d_in, const int* in_sizes, int n_in,
                              void* d_out, int out_size, void* d_ws, size_t ws_size,
                              hipStream_t stream) {
  const float* hidden = (const float*)d_in[0];
  const float* tw     = (const float*)d_in[1];
  const int*   ids    = (const int*)d_in[2];
  const float* wgu    = (const float*)d_in[3];
  const float* sgu    = (const float*)d_in[4];
  const float* wdn    = (const float*)d_in[5];
  const float* sdn    = (const float*)d_in[6];
  float* out = (float*)d_out;
  int* wsI = (int*)d_ws;

  hipMemsetAsync(d_ws, 0, 512, stream);
  k_count  <<<16, 256, 0, stream>>>(ids, wsI);
  k_scan   <<<1, 1, 0, stream>>>(wsI);
  k_scatter<<<16, 256, 0, stream>>>(ids, tw, wsI);

  const size_t NEED = 65536ull + (52ull << 20);
  if (ws_size >= NEED) {
    unsigned short* hb  = (unsigned short*)((char*)d_ws + 65536);
    unsigned short* act = hb + (size_t)T_TOK * HDIM;
    float*          oe  = (float*)(act + (size_t)NENT * FDIM);

    k_cast_h<<<2048, 256, 0, stream>>>(hidden, hb);

    dim3 g1(WMAX, 32);
    k_gemm1n<<<g1, 256, 0, stream>>>(hb, wgu, sgu, wsI, act);
    dim3 g2(WMAX, 32);
    k_gemm2n<<<g2, 256, 0, stream>>>(wdn, sdn, wsI, act, oe);
    k_reduce<<<T_TOK * HDIM / 4 / 256, 256, 0, stream>>>(wsI, oe, out);
  } else {
    unsigned short* act = (unsigned short*)((char*)d_ws + 65536);
    hipMemsetAsync(d_out, 0, (size_t)T_TOK * HDIM * sizeof(float), stream);
    dim3 g1(NENT / 128, NEXP, FDIM / 64);
    k_gemm1_fb<<<g1, 256, 0, stream>>>(hidden, wgu, sgu, wsI, act);
    dim3 g2(NENT / 128, NEXP, HDIM / 128);
    k_gemm2_fb<<<g2, 256, 0, stream>>>(wdn, sdn, wsI, act, out);
  }
}